// Round 12
// baseline (62.908 us; speedup 1.0000x reference)
//
#include <hip/hip_runtime.h>
#include <hip/hip_bf16.h>

#define B 16
#define S 4096
#define D 256
#define U 256
#define ROWS 64
#define NCHK (S / ROWS)  // 64 chunks per batch

typedef short short8 __attribute__((ext_vector_type(8)));
typedef float f32x4 __attribute__((ext_vector_type(4)));

__device__ __forceinline__ ushort f2bf(float f) {
    union { float f; uint u; } x{f};
    uint r = (x.u + 0x7fffu + ((x.u >> 16) & 1u)) >> 16;  // RNE
    return (ushort)r;
}

__device__ __forceinline__ float fast_tanh(float x) {
    float e = __expf(2.0f * x);
    return 1.0f - 2.0f * __builtin_amdgcn_rcpf(e + 1.0f);
}

__device__ __forceinline__ void agent_store(float* p, float v) {
    __hip_atomic_store(p, v, __ATOMIC_RELAXED, __HIP_MEMORY_SCOPE_AGENT);
}
__device__ __forceinline__ float agent_load(const float* p) {
    return __hip_atomic_load(p, __ATOMIC_RELAXED, __HIP_MEMORY_SCOPE_AGENT);
}

// KA: setup. blocks 0..15: pqb GEMV (ILP-parallel); blocks 16..23: W1 pack.
__global__ void ka_setup(const float* __restrict__ query, const float* __restrict__ W2,
                         const float* __restrict__ b2, const float* __restrict__ b1,
                         const float* __restrict__ W1, float* __restrict__ pqb,
                         ushort* __restrict__ W1p) {
    __shared__ float pp[4][U];
    int bid = blockIdx.x, t = threadIdx.x;
    if (bid < 16) {
        const float* qb = query + bid * D;
        int u0 = (t & 63) * 4, dc = t >> 6;
        float4 a = {0.f, 0.f, 0.f, 0.f};
#pragma unroll 16
        for (int i = 0; i < 64; ++i) {
            int d = dc * 64 + i;
            float qd = qb[d];
            float4 wv = *(const float4*)&W2[d * U + u0];
            a.x = fmaf(qd, wv.x, a.x);
            a.y = fmaf(qd, wv.y, a.y);
            a.z = fmaf(qd, wv.z, a.z);
            a.w = fmaf(qd, wv.w, a.w);
        }
        *(float4*)&pp[dc][u0] = a;
        __syncthreads();
        pqb[bid * U + t] = pp[0][t] + pp[1][t] + pp[2][t] + pp[3][t] + b2[t] + b1[t];
    } else {
        int kk = bid - 16;
        int l = t & 63, g = t >> 6;
        int colu0 = l & 15;
        int k0 = kk * 32 + (l >> 4) * 8;
#pragma unroll
        for (int i = 0; i < 4; ++i) {
            int nt = g * 4 + i;
            int colu = nt * 16 + colu0;
            ushort* dst = W1p + (((nt * 8) + kk) * 64 + l) * 8;
#pragma unroll
            for (int e = 0; e < 8; ++e) dst[e] = f2bf(W1[(k0 + e) * U + colu]);
        }
    }
}

// KB: per 64-row chunk (r5-verified math) + fused last-block-ticket finisher.
// Cross-XCD handoff via relaxed agent-scope (sc1) stores/loads — NO release fences.
__global__ __launch_bounds__(256, 4) void kb_scores(
    const float* __restrict__ values, const ushort* __restrict__ W1p,
    const float* __restrict__ pqb, const float* __restrict__ V,
    const float* __restrict__ bV, float* __restrict__ cstats,
    float* __restrict__ cpart, int* __restrict__ syncp,
    float* __restrict__ wout, float* __restrict__ ctx) {
    __shared__ ushort Alds[ROWS * 256];  // 32 KB, XOR-swizzled bf16 tile
    __shared__ float red[4][ROWS];
    __shared__ float wch[ROWS];
    __shared__ float scl[NCHK];
    __shared__ float stats2[2];
    __shared__ int lastFlag;
    const int bid = blockIdx.x;
    const int t = threadIdx.x;
    const int w = t >> 6, l = t & 63;
    char* lds = (char*)Alds;
    const int b = bid >> 6;
    const int s0 = (bid & 63) * ROWS;

    // stage 64x256 fp32 -> bf16 LDS, byte ^= (row&7)<<4
    const float* src = values + ((size_t)(b * S + s0)) * D;
#pragma unroll
    for (int i = 0; i < 16; ++i) {
        int row = i * 4 + w;
        int col = l * 4;
        float4 v = *(const float4*)&src[row * 256 + col];
        ushort4 h;
        h.x = f2bf(v.x); h.y = f2bf(v.y); h.z = f2bf(v.z); h.w = f2bf(v.w);
        int byte = (row * 512 + col * 2) ^ ((row & 7) << 4);
        *(ushort4*)(lds + byte) = h;
    }
    __syncthreads();

    // MFMA scores
    const int lrow = l & 15, lk = l >> 4;
    f32x4 acc[4][4];
#pragma unroll
    for (int mt = 0; mt < 4; ++mt)
#pragma unroll
        for (int nt = 0; nt < 4; ++nt) acc[mt][nt] = (f32x4){0.f, 0.f, 0.f, 0.f};

    for (int kk = 0; kk < 8; ++kk) {
        short8 afr[4], bfr[4];
#pragma unroll
        for (int mt = 0; mt < 4; ++mt) {
            int row = mt * 16 + lrow;
            int byte = (row * 512 + kk * 64 + lk * 16) ^ ((row & 7) << 4);
            afr[mt] = *(const short8*)(lds + byte);
        }
#pragma unroll
        for (int nt = 0; nt < 4; ++nt)
            bfr[nt] = *(const short8*)&W1p[((((w * 4 + nt) * 8) + kk) * 64 + l) * 8];
#pragma unroll
        for (int mt = 0; mt < 4; ++mt)
#pragma unroll
            for (int nt = 0; nt < 4; ++nt)
                acc[mt][nt] = __builtin_amdgcn_mfma_f32_16x16x32_bf16(
                    afr[mt], bfr[nt], acc[mt][nt], 0, 0, 0);
    }

    // epilogue: tanh, .V, reduce over u
    float bb[4], vv[4];
#pragma unroll
    for (int nt = 0; nt < 4; ++nt) {
        int u = (w * 4 + nt) * 16 + lrow;
        bb[nt] = pqb[b * U + u];
        vv[nt] = V[u];
    }
#pragma unroll
    for (int mt = 0; mt < 4; ++mt) {
#pragma unroll
        for (int r = 0; r < 4; ++r) {
            float s = 0.f;
#pragma unroll
            for (int nt = 0; nt < 4; ++nt)
                s += fast_tanh(acc[mt][nt][r] + bb[nt]) * vv[nt];
            s += __shfl_xor(s, 1);
            s += __shfl_xor(s, 2);
            s += __shfl_xor(s, 4);
            s += __shfl_xor(s, 8);
            if (lrow == 0) red[w][mt * 16 + lk * 4 + r] = s;
        }
    }
    __syncthreads();

    if (t < ROWS) {  // wave 0: chunk stats + unnormalized weights (agent stores)
        float s = red[0][t] + red[1][t] + red[2][t] + red[3][t] + bV[0];
        float m = s;
#pragma unroll
        for (int off = 32; off; off >>= 1) m = fmaxf(m, __shfl_xor(m, off));
        float z0 = __expf(s - m);
        wch[t] = z0;
        agent_store(&wout[b * S + s0 + t], z0);  // finisher rescales in place
        float z = z0;
#pragma unroll
        for (int off = 32; off; off >>= 1) z += __shfl_xor(z, off);
        if (t == 0) {
            agent_store(&cstats[2 * bid], m);
            agent_store(&cstats[2 * bid + 1], z);
        }
    }
    __syncthreads();

    // partial context from bf16 LDS: thread t owns column t (conflict-free u16 reads)
    union { uint i; float f; } cv;
    float cacc = 0.f;
#pragma unroll 8
    for (int r = 0; r < ROWS; ++r) {
        int byte = (r * 512 + t * 2) ^ ((r & 7) << 4);
        ushort u = *(const ushort*)(lds + byte);
        cv.i = (uint)u << 16;
        cacc = fmaf(wch[r], cv.f, cacc);
    }
    agent_store(&cpart[(size_t)bid * D + t], cacc);

    // last-block ticket per batch. __syncthreads drains each wave's stores
    // (compiler emits s_waitcnt vmcnt(0) before s_barrier) — completed sc1
    // stores are device-visible, so no release fence is needed.
    __syncthreads();
    if (t == 0) {
        int old = __hip_atomic_fetch_add(&syncp[b], 1, __ATOMIC_RELAXED,
                                         __HIP_MEMORY_SCOPE_AGENT);
        lastFlag = (old == NCHK - 1);
    }
    __syncthreads();
    if (!lastFlag) return;

    // ---- finisher for batch b (exactly one block per batch) ----
    if (t < NCHK) {
        float m = agent_load(&cstats[2 * (b * NCHK + t)]);
        float z = agent_load(&cstats[2 * (b * NCHK + t) + 1]);
        float M = m;
#pragma unroll
        for (int off = 32; off; off >>= 1) M = fmaxf(M, __shfl_xor(M, off));
        float zz = z * __expf(m - M);
#pragma unroll
        for (int off = 32; off; off >>= 1) zz += __shfl_xor(zz, off);
        scl[t] = __expf(m - M);
        if (t == 0) { stats2[0] = M; stats2[1] = zz; }
    }
    __syncthreads();
    float invZ = 1.0f / stats2[1];

    // ctx: thread t owns dim t
    float ctxacc = 0.f;
#pragma unroll 8
    for (int c = 0; c < NCHK; ++c)
        ctxacc = fmaf(scl[c], agent_load(&cpart[(size_t)(b * NCHK + c) * D + t]), ctxacc);
    ctx[b * D + t] = ctxacc * invZ;

    // wout rescale in place: 16 entries per thread
#pragma unroll
    for (int i = 0; i < 16; ++i) {
        int ss = i * 256 + t;
        float z0 = agent_load(&wout[b * S + ss]);
        wout[b * S + ss] = z0 * scl[ss >> 6] * invZ;
    }
}

extern "C" void kernel_launch(void* const* d_in, const int* in_sizes, int n_in,
                              void* d_out, int out_size, void* d_ws, size_t ws_size,
                              hipStream_t stream) {
    const float* values = (const float*)d_in[0];
    const float* query  = (const float*)d_in[1];
    const float* W1     = (const float*)d_in[2];
    const float* b1     = (const float*)d_in[3];
    const float* W2     = (const float*)d_in[4];
    const float* b2     = (const float*)d_in[5];
    const float* V      = (const float*)d_in[6];
    const float* bV     = (const float*)d_in[7];

    float* out  = (float*)d_out;
    float* ctx  = out;          // [B, D]
    float* wout = out + B * D;  // [B, S, 1]

    float* ws     = (float*)d_ws;
    float* pqb    = ws;                    // 4096
    float* cstats = pqb + B * U;           // 2*B*NCHK = 2048
    float* cpart  = cstats + 2 * B * NCHK; // B*NCHK*D = 262144
    ushort* W1p   = (ushort*)(cpart + (size_t)B * NCHK * D);  // 65536 ushorts
    int* syncp    = (int*)(W1p + 65536);   // [0..15] per-batch tickets

    hipMemsetAsync(syncp, 0, 16 * sizeof(int), stream);
    ka_setup<<<24, 256, 0, stream>>>(query, W2, b2, b1, W1, pqb, W1p);
    kb_scores<<<B * NCHK, 256, 0, stream>>>(values, W1p, pqb, V, bV,
                                            cstats, cpart, syncp, wout, ctx);
}

// Round 13
// 42.564 us; speedup vs baseline: 1.4780x; 1.4780x over previous
//
#include <hip/hip_runtime.h>
#include <hip/hip_bf16.h>

#define B 16
#define S 4096
#define D 256
#define U 256
#define ROWS 64    // rows per block in score kernel
#define NCHK (S / ROWS)  // 64 chunks per batch

typedef short short8 __attribute__((ext_vector_type(8)));
typedef float f32x4 __attribute__((ext_vector_type(4)));

__device__ __forceinline__ ushort f2bf(float f) {
    union { float f; uint u; } x{f};
    uint r = (x.u + 0x7fffu + ((x.u >> 16) & 1u)) >> 16;  // RNE
    return (ushort)r;
}

__device__ __forceinline__ float fast_tanh(float x) {
    float e = __expf(2.0f * x);
    return 1.0f - 2.0f * __builtin_amdgcn_rcpf(e + 1.0f);
}

// KA: fused setup.
//  blocks 0..15 : pqb[b][u] = query[b,:].W2[:,u] + b2[u] + b1[u]
//  blocks 16..23: pack W1 (fp32 [D][U]) into bf16 MFMA B-fragment order, one kk each
__global__ void ka_setup(const float* __restrict__ q, const float* __restrict__ W2,
                         const float* __restrict__ b2, const float* __restrict__ b1,
                         const float* __restrict__ W1, float* __restrict__ pqb,
                         ushort* __restrict__ W1p) {
    int bid = blockIdx.x, t = threadIdx.x;
    if (bid < 16) {
        int b = bid, u = t;
        const float* qb = q + b * D;
        float acc = b2[u] + b1[u];
#pragma unroll 8
        for (int d = 0; d < D; ++d)
            acc = fmaf(qb[d], W2[d * U + u], acc);
        pqb[b * U + u] = acc;
    } else {
        int kk = bid - 16;
        int l = t & 63, g = t >> 6;
        int colu0 = l & 15;
        int k0 = kk * 32 + (l >> 4) * 8;
#pragma unroll
        for (int i = 0; i < 4; ++i) {
            int nt = g * 4 + i;
            int colu = nt * 16 + colu0;
            ushort* dst = W1p + (((nt * 8) + kk) * 64 + l) * 8;
#pragma unroll
            for (int e = 0; e < 8; ++e) dst[e] = f2bf(W1[(k0 + e) * U + colu]);
        }
    }
}

// KB: per 64-row chunk: scores via bf16 MFMA, chunk softmax stats (m_c, z_c),
// and unnormalized partial context from the bf16 LDS copy (single HBM pass).
// Round-13 edits vs r5: (1) staging split — issue all 16 global loads into
// registers, then convert+ds_write (T14 issue-early/write-late);
// (2) kk loop fully unrolled so B-fragment loads can hoist/pipeline.
__global__ __launch_bounds__(256, 4) void kb_scores(
    const float* __restrict__ values, const ushort* __restrict__ W1p,
    const float* __restrict__ pqb, const float* __restrict__ V,
    const float* __restrict__ bV, float* __restrict__ scores,
    float* __restrict__ cstats, float* __restrict__ cpart) {
    __shared__ ushort Alds[ROWS * 256];  // 32 KB, XOR-swizzled bf16 tile
    __shared__ float red[4][ROWS];
    __shared__ float wch[ROWS];
    int b = blockIdx.x >> 6;
    int s0 = (blockIdx.x & 63) * ROWS;
    int t = threadIdx.x;
    int w = t >> 6, l = t & 63;
    char* lds = (char*)Alds;

    // ---- stage 64x256 fp32 -> bf16 LDS, byte ^= (row&7)<<4 ----
    // Phase 1: issue ALL 16 float4 loads (64 VGPRs) so they overlap in flight.
    const float* src = values + ((size_t)(b * S + s0)) * D;
    float4 vreg[16];
#pragma unroll
    for (int i = 0; i < 16; ++i)
        vreg[i] = *(const float4*)&src[(i * 4 + w) * 256 + l * 4];
    // Phase 2: convert + swizzled LDS write.
#pragma unroll
    for (int i = 0; i < 16; ++i) {
        int row = i * 4 + w;
        int col = l * 4;
        ushort4 h;
        h.x = f2bf(vreg[i].x); h.y = f2bf(vreg[i].y);
        h.z = f2bf(vreg[i].z); h.w = f2bf(vreg[i].w);
        int byte = (row * 512 + col * 2) ^ ((row & 7) << 4);
        *(ushort4*)(lds + byte) = h;
    }
    __syncthreads();

    // ---- MFMA scores (kk fully unrolled) ----
    int lrow = l & 15, lk = l >> 4;
    f32x4 acc[4][4];
#pragma unroll
    for (int mt = 0; mt < 4; ++mt)
#pragma unroll
        for (int nt = 0; nt < 4; ++nt) acc[mt][nt] = (f32x4){0.f, 0.f, 0.f, 0.f};

#pragma unroll
    for (int kk = 0; kk < 8; ++kk) {
        short8 afr[4], bfr[4];
#pragma unroll
        for (int nt = 0; nt < 4; ++nt) {
            int ntile = w * 4 + nt;
            bfr[nt] = *(const short8*)&W1p[(((ntile * 8) + kk) * 64 + l) * 8];
        }
#pragma unroll
        for (int mt = 0; mt < 4; ++mt) {
            int row = mt * 16 + lrow;
            int byte = (row * 512 + kk * 64 + lk * 16) ^ ((row & 7) << 4);
            afr[mt] = *(const short8*)(lds + byte);
        }
#pragma unroll
        for (int mt = 0; mt < 4; ++mt)
#pragma unroll
            for (int nt = 0; nt < 4; ++nt)
                acc[mt][nt] = __builtin_amdgcn_mfma_f32_16x16x32_bf16(
                    afr[mt], bfr[nt], acc[mt][nt], 0, 0, 0);
    }

    // ---- epilogue: tanh, .V, reduce over u ----
    float bb[4], vv[4];
#pragma unroll
    for (int nt = 0; nt < 4; ++nt) {
        int u = (w * 4 + nt) * 16 + lrow;
        bb[nt] = pqb[b * U + u];
        vv[nt] = V[u];
    }
#pragma unroll
    for (int mt = 0; mt < 4; ++mt) {
#pragma unroll
        for (int r = 0; r < 4; ++r) {
            float s = 0.f;
#pragma unroll
            for (int nt = 0; nt < 4; ++nt)
                s += fast_tanh(acc[mt][nt][r] + bb[nt]) * vv[nt];
            s += __shfl_xor(s, 1);
            s += __shfl_xor(s, 2);
            s += __shfl_xor(s, 4);
            s += __shfl_xor(s, 8);
            if (lrow == 0) red[w][mt * 16 + lk * 4 + r] = s;
        }
    }
    __syncthreads();
    if (t < ROWS) {  // wave 0
        float s = red[0][t] + red[1][t] + red[2][t] + red[3][t] + bV[0];
        scores[b * S + s0 + t] = s;
        float m = s;
#pragma unroll
        for (int off = 32; off; off >>= 1) m = fmaxf(m, __shfl_xor(m, off));
        float z0 = __expf(s - m);
        wch[t] = z0;
        float z = z0;
#pragma unroll
        for (int off = 32; off; off >>= 1) z += __shfl_xor(z, off);
        if (t == 0) {
            cstats[2 * blockIdx.x] = m;
            cstats[2 * blockIdx.x + 1] = z;
        }
    }
    __syncthreads();

    // partial context from the bf16 LDS copy: thread t owns column t.
    union { uint i; float f; } cv;
    float cacc = 0.f;
#pragma unroll 8
    for (int r = 0; r < ROWS; ++r) {
        int byte = (r * 512 + t * 2) ^ ((r & 7) << 4);
        ushort u = *(const ushort*)(lds + byte);
        cv.i = (uint)u << 16;
        cacc = fmaf(wch[r], cv.f, cacc);
    }
    cpart[(size_t)blockIdx.x * D + t] = cacc;
}

// KC: finisher. 4 blocks per batch (q = quarter).
__global__ void kc_final(const float* __restrict__ scores, const float* __restrict__ cstats,
                         const float* __restrict__ cpart, float* __restrict__ wout,
                         float* __restrict__ ctx) {
    __shared__ float scl[NCHK];
    __shared__ float stats[2];
    __shared__ float part[4][64];
    int b = blockIdx.x >> 2, q = blockIdx.x & 3;
    int t = threadIdx.x;

    if (t < 64) {
        float m = cstats[2 * (b * NCHK + t)];
        float z = cstats[2 * (b * NCHK + t) + 1];
        float M = m;
#pragma unroll
        for (int off = 32; off; off >>= 1) M = fmaxf(M, __shfl_xor(M, off));
        float zz = z * __expf(m - M);
#pragma unroll
        for (int off = 32; off; off >>= 1) zz += __shfl_xor(zz, off);
        scl[t] = __expf(m - M);
        if (t == 0) { stats[0] = M; stats[1] = zz; }
    }
    __syncthreads();
    float M = stats[0];
    float invZ = 1.0f / stats[1];

    int tq = t >> 6, dl = t & 63;
    int d = q * 64 + dl;
    float acc = 0.f;
#pragma unroll
    for (int i = 0; i < 16; ++i) {
        int c = tq * 16 + i;
        acc = fmaf(scl[c], cpart[(size_t)(b * NCHK + c) * D + d], acc);
    }
    part[tq][dl] = acc;

#pragma unroll
    for (int i = 0; i < 4; ++i) {
        int s = q * 1024 + i * 256 + t;
        wout[b * S + s] = __expf(scores[b * S + s] - M) * invZ;
    }
    __syncthreads();
    if (t < 64)
        ctx[b * D + q * 64 + t] =
            (part[0][t] + part[1][t] + part[2][t] + part[3][t]) * invZ;
}

extern "C" void kernel_launch(void* const* d_in, const int* in_sizes, int n_in,
                              void* d_out, int out_size, void* d_ws, size_t ws_size,
                              hipStream_t stream) {
    const float* values = (const float*)d_in[0];
    const float* query  = (const float*)d_in[1];
    const float* W1     = (const float*)d_in[2];
    const float* b1     = (const float*)d_in[3];
    const float* W2     = (const float*)d_in[4];
    const float* b2     = (const float*)d_in[5];
    const float* V      = (const float*)d_in[6];
    const float* bV     = (const float*)d_in[7];

    float* out  = (float*)d_out;
    float* ctx  = out;          // [B, D]
    float* wout = out + B * D;  // [B, S, 1]

    float* ws     = (float*)d_ws;
    float* pqb    = ws;                 // B*U          = 4096
    float* scores = pqb + B * U;        // B*S          = 65536
    float* cstats = scores + B * S;     // 2*B*NCHK     = 2048
    float* cpart  = cstats + 2048;      // B*NCHK*D     = 262144
    ushort* W1p   = (ushort*)(cpart + B * NCHK * D);  // 65536 ushorts

    ka_setup<<<24, 256, 0, stream>>>(query, W2, b2, b1, W1, pqb, W1p);
    kb_scores<<<B * NCHK, 256, 0, stream>>>(values, W1p, pqb, V, bV, scores, cstats, cpart);
    kc_final<<<B * 4, 256, 0, stream>>>(scores, cstats, cpart, wout, ctx);
}